// Round 15
// baseline (194.266 us; speedup 1.0000x reference)
//
#include <hip/hip_runtime.h>

// Problem constants
#define B_   32
#define T_   2048
#define IN_  1024
#define OUT_ 256
#define M_   (B_ * T_)   // 65536

// Wave-streaming GEMM: NO barriers, NO LDS staging in the main loop.
// Block = 256 threads = 4 waves; wave w owns rows [bm0+32w, bm0+32w+32) x all
// 256 cols. A read directly (fp32->bf16 in reg, 1-step prefetch); B fragments
// read directly from L2-resident bf16 W (a row of Wb IS an MFMA B-frag).
#define BM 128
#define THREADS 256
#define TPB 16              // time-tiles per batch: T/BM
#define NSTEP (IN_ / 32)    // 32 K-steps

// Scan chunking: LC=32 -> 4 chunks per block tile.
#define LC 32
#define XPAD 264            // x-tile row pitch (bf16)

// LDS: x-tile 66KB + ce 4KB + ca 4KB = 74KB -> 2 blocks/CU (8 waves/CU).
#define XT_BYTES (BM * XPAD * 2)              // 67584
#define SMEM_BYTES (XT_BYTES + 8192)          // 75776

typedef __attribute__((ext_vector_type(4))) float f32x4;
typedef __attribute__((ext_vector_type(8))) __bf16 bf16x8;

// fp32 -> bf16 round-to-nearest-even
__device__ __forceinline__ unsigned int f2bf_pk(float a, float b) {
    unsigned int ua = __float_as_uint(a);
    unsigned int ub = __float_as_uint(b);
    ua = (ua + 0x7fffu + ((ua >> 16) & 1u)) >> 16;
    ub = (ub + 0x7fffu + ((ub >> 16) & 1u)) >> 16;
    return ua | (ub << 16);
}
__device__ __forceinline__ unsigned short f2bf1(float a) {
    unsigned int ua = __float_as_uint(a);
    return (unsigned short)((ua + 0x7fffu + ((ua >> 16) & 1u)) >> 16);
}
__device__ __forceinline__ float bf2f(unsigned short s) {
    return __uint_as_float((unsigned int)s << 16);
}

// ---------------------------------------------------------------------------
// One-shot W fp32 -> bf16 (512 KB) + zero ticket/flag region (block 0).
// ---------------------------------------------------------------------------
__global__ __launch_bounds__(256) void convert_w_init(const float* __restrict__ W,
                                                      unsigned short* __restrict__ Wb,
                                                      unsigned int* __restrict__ flags) {
    const int i = blockIdx.x * 256 + threadIdx.x;  // float4 index
    const float4 v = ((const float4*)W)[i];
    uint2 o;
    o.x = f2bf_pk(v.x, v.y);
    o.y = f2bf_pk(v.z, v.w);
    ((uint2*)Wb)[i] = o;
    if (blockIdx.x == 0) {
        flags[threadIdx.x] = 0u;
        flags[256 + threadIdx.x] = 0u;
        if (threadIdx.x == 0) flags[512] = 0u;   // ticket
    }
}

// ---------------------------------------------------------------------------
// Fused kernel: barrier-free streaming GEMM + chunk scans + decoupled
// lookback + final scan to out.
// Per wave, per K-step (32 of them): 4 A float4 loads (next step, prefetch),
// 16 B bf16x8 loads (this step, L2-hot), 8 cvt_pk, 32 MFMA. All 4 waves
// fully independent until the epilogue's first __syncthreads.
// Accumulation order per acc[m][n] identical to the round-9 kernel
// (ascending K-steps of 32) -> bit-identical output.
// ---------------------------------------------------------------------------
__global__ __launch_bounds__(THREADS, 2) void fused_all(
    const float* __restrict__ A, const unsigned short* __restrict__ Wb,
    const float* __restrict__ bias, const float* __restrict__ decay,
    float* __restrict__ out, float* __restrict__ localend,
    unsigned int* __restrict__ flags) {
    __shared__ __align__(16) char smem[SMEM_BYTES];
    __shared__ int s_tk;

    const int tid  = threadIdx.x;
    const int lane = tid & 63;
    const int w    = tid >> 6;     // wave 0..3 -> rows w*32..w*32+31
    const int l15  = lane & 15;
    const int l4   = lane >> 4;    // 0..3

    if (tid == 0) s_tk = (int)atomicAdd(&flags[512], 1u);   // device-scope ticket
    __syncthreads();
    const int p    = s_tk;           // m-tile position, 0..511
    const int jb   = p & (TPB - 1);  // tile index within batch
    const int base = p - jb;         // first tile of this batch
    const int bm0  = p * BM;

    // A pointers: lane covers rows (w*32 + l15) and (+16), k-slice l4*8.
    const float* pA0 = A + (size_t)(bm0 + w * 32 + l15) * IN_ + l4 * 8;
    const float* pA1 = pA0 + (size_t)16 * IN_;
    // B base: col = n*16 + l15 -> byte offset n*32768 + l15*2048 + l4*16.
    const char* WbB = (const char*)Wb + (size_t)l15 * (IN_ * 2) + l4 * 16;

    f32x4 acc[2][16] = {};

    // prefetch A for step 0
    float4 a00 = *(const float4*)(pA0);
    float4 a01 = *(const float4*)(pA0 + 4);
    float4 a10 = *(const float4*)(pA1);
    float4 a11 = *(const float4*)(pA1 + 4);

#pragma unroll 1
    for (int k0 = 0; k0 < IN_; k0 += 32) {
        // cvt current A regs -> fragments
        union { uint4 u; bf16x8 v; } t0, t1;
        t0.u.x = f2bf_pk(a00.x, a00.y); t0.u.y = f2bf_pk(a00.z, a00.w);
        t0.u.z = f2bf_pk(a01.x, a01.y); t0.u.w = f2bf_pk(a01.z, a01.w);
        t1.u.x = f2bf_pk(a10.x, a10.y); t1.u.y = f2bf_pk(a10.z, a10.w);
        t1.u.z = f2bf_pk(a11.x, a11.y); t1.u.w = f2bf_pk(a11.z, a11.w);
        const bf16x8 af0 = t0.v;
        const bf16x8 af1 = t1.v;
        // issue next step's A loads (HBM stream; covered by this step's work)
        if (k0 + 32 < IN_) {
            a00 = *(const float4*)(pA0 + k0 + 32);
            a01 = *(const float4*)(pA0 + k0 + 36);
            a10 = *(const float4*)(pA1 + k0 + 32);
            a11 = *(const float4*)(pA1 + k0 + 36);
        }
        // B fragments: 16 direct loads from L2-hot Wb
        const char* pb = WbB + (k0 << 1);
        bf16x8 bfr[16];
#pragma unroll
        for (int n = 0; n < 16; ++n)
            bfr[n] = *(const bf16x8*)(pb + (size_t)n * 32768);
        // 32 MFMA
#pragma unroll
        for (int n = 0; n < 16; ++n) {
            acc[0][n] = __builtin_amdgcn_mfma_f32_16x16x32_bf16(af0, bfr[n], acc[0][n], 0, 0, 0);
            acc[1][n] = __builtin_amdgcn_mfma_f32_16x16x32_bf16(af1, bfr[n], acc[1][n], 0, 0, 0);
        }
    }

    unsigned short* xt = (unsigned short*)smem;
    float* ceL = (float*)(smem + XT_BYTES);        // [4][256] chunk-local ends
    float* caL = ceL + 4 * OUT_;                   // [4][256] chunk carry-ins

    // --- x = acc + bias -> bf16 x-tile [128][XPAD] ---
#pragma unroll
    for (int n = 0; n < 16; ++n) {
        const int col = n * 16 + l15;
        const float bv = bias[col];
#pragma unroll
        for (int m = 0; m < 2; ++m) {
            const int r0 = w * 32 + m * 16 + (l4 << 2);
#pragma unroll
            for (int r = 0; r < 4; ++r)
                xt[(r0 + r) * XPAD + col] = f2bf1(acc[m][n][r] + bv);
        }
    }
    __syncthreads();

    // --- chunk-local scans (seed 0) -> ceL ---
    for (int task = tid; task < 4 * OUT_; task += THREADS) {
        const int cl  = task >> 8;
        const int col = task & 255;
        const float alpha = decay[col];
        const float om = 1.0f - alpha;
        float u = 0.0f;
        const unsigned short* px = &xt[(cl * LC) * XPAD + col];
#pragma unroll
        for (int t = 0; t < LC; ++t)
            u = fmaf(alpha, u, om * bf2f(px[t * XPAD]));
        ceL[cl * OUT_ + col] = u;
    }
    __syncthreads();

    // --- fold 4 chunks -> 128-step composite; publish (AGENT scope) ---
    float a32 = 0.f, a128 = 0.f;
    if (tid < OUT_) {
        const float alpha_c = decay[tid];
        a32 = alpha_c;
#pragma unroll
        for (int i = 1; i < LC; ++i) a32 *= alpha_c;   // alpha^32
        const float t2 = a32 * a32;
        a128 = t2 * t2;                                // alpha^128
        float le = ceL[tid];
        le = fmaf(a32, le, ceL[OUT_ + tid]);
        le = fmaf(a32, le, ceL[2 * OUT_ + tid]);
        le = fmaf(a32, le, ceL[3 * OUT_ + tid]);
        __hip_atomic_store(&localend[(size_t)p * OUT_ + tid], le,
                           __ATOMIC_RELAXED, __HIP_MEMORY_SCOPE_AGENT);
    }
    __syncthreads();   // payload stores drained before flag
    if (tid == 0)
        __hip_atomic_store(&flags[p], 1u, __ATOMIC_RELEASE, __HIP_MEMORY_SCOPE_AGENT);
    // --- wait for predecessors of this batch (raking) ---
    if (tid < jb) {
        while (__hip_atomic_load(&flags[base + tid], __ATOMIC_ACQUIRE,
                                 __HIP_MEMORY_SCOPE_AGENT) == 0u)
            __builtin_amdgcn_s_sleep(2);
    }
    __syncthreads();

    // --- compose carry-in: fold predecessors' composites with alpha^128 ---
    if (tid < OUT_) {
        float cin = 0.0f;
#pragma unroll
        for (int i = 0; i < TPB - 1; ++i) {
            float v = __hip_atomic_load(&localend[(size_t)(base + i) * OUT_ + tid],
                                        __ATOMIC_RELAXED, __HIP_MEMORY_SCOPE_AGENT);
            if (i < jb) cin = fmaf(a128, cin, v);
        }
        caL[tid] = cin;
        const float c1 = fmaf(a32, cin, ceL[tid]);
        const float c2 = fmaf(a32, c1, ceL[OUT_ + tid]);
        const float c3 = fmaf(a32, c2, ceL[2 * OUT_ + tid]);
        caL[OUT_ + tid] = c1;
        caL[2 * OUT_ + tid] = c2;
        caL[3 * OUT_ + tid] = c3;
    }
    __syncthreads();

    // --- final scan: seed from chunk carry, write u straight to out ---
    for (int task = tid; task < 4 * OUT_; task += THREADS) {
        const int cl  = task >> 8;
        const int col = task & 255;
        const float alpha = decay[col];
        const float om = 1.0f - alpha;
        float u = caL[cl * OUT_ + col];
        const unsigned short* px = &xt[(cl * LC) * XPAD + col];
        float* po = &out[(size_t)(bm0 + cl * LC) * OUT_ + col];
#pragma unroll
        for (int t = 0; t < LC; ++t) {
            u = fmaf(alpha, u, om * bf2f(px[t * XPAD]));
            po[(size_t)t * OUT_] = u;
        }
    }
}

// ---------------------------------------------------------------------------
// Fallback path (ws too small): fp32 GEMM + simple scan, known good.
// ---------------------------------------------------------------------------
__global__ __launch_bounds__(256) void gemm_bias(const float* __restrict__ A,
                                                 const float* __restrict__ W,
                                                 const float* __restrict__ bias,
                                                 float* __restrict__ C) {
    __shared__ float As[16][64 + 4];
    __shared__ float Ws[16][64 + 4];
    const int bm = blockIdx.y * 64;
    const int bn = blockIdx.x * 64;
    const int tid = threadIdx.x;
    const int tx = tid & 15, ty = tid >> 4;
    const int lr = tid >> 2, lc = (tid & 3) << 2;
    float acc[4][4] = {};
    const float* Ap = A + (size_t)(bm + lr) * IN_ + lc;
    const float* Wp = W + (size_t)(bn + lr) * IN_ + lc;
    for (int k0 = 0; k0 < IN_; k0 += 16) {
        const float4 a = *(const float4*)(Ap + k0);
        const float4 w = *(const float4*)(Wp + k0);
        __syncthreads();
        As[lc + 0][lr] = a.x; As[lc + 1][lr] = a.y; As[lc + 2][lr] = a.z; As[lc + 3][lr] = a.w;
        Ws[lc + 0][lr] = w.x; Ws[lc + 1][lr] = w.y; Ws[lc + 2][lr] = w.z; Ws[lc + 3][lr] = w.w;
        __syncthreads();
#pragma unroll
        for (int kk = 0; kk < 16; ++kk) {
            const float4 av = *(const float4*)&As[kk][ty << 2];
            const float4 wv = *(const float4*)&Ws[kk][tx << 2];
            const float a0[4] = {av.x, av.y, av.z, av.w};
            const float w0[4] = {wv.x, wv.y, wv.z, wv.w};
#pragma unroll
            for (int i = 0; i < 4; ++i)
#pragma unroll
                for (int j = 0; j < 4; ++j) acc[i][j] = fmaf(a0[i], w0[j], acc[i][j]);
        }
    }
#pragma unroll
    for (int i = 0; i < 4; ++i) {
        const size_t row = (size_t)(bm + (ty << 2) + i);
#pragma unroll
        for (int j = 0; j < 4; ++j)
            C[row * OUT_ + bn + (tx << 2) + j] = acc[i][j] + bias[bn + (tx << 2) + j];
    }
}

__global__ __launch_bounds__(OUT_) void scan_simple(float* __restrict__ C,
                                                    const float* __restrict__ decay) {
    const int b = blockIdx.x;
    const int o = threadIdx.x;
    const float alpha = decay[o];
    const float om = 1.0f - alpha;
    float u = 0.0f;
    float* p = C + (size_t)b * T_ * OUT_ + o;
    for (int t = 0; t < T_; ++t) {
        const float x = p[(size_t)t * OUT_];
        u = fmaf(alpha, u, om * x);
        p[(size_t)t * OUT_] = u;
    }
}

extern "C" void kernel_launch(void* const* d_in, const int* in_sizes, int n_in,
                              void* d_out, int out_size, void* d_ws, size_t ws_size,
                              hipStream_t stream) {
    const float* inputs = (const float*)d_in[0];
    const float* weight = (const float*)d_in[1];
    const float* bias   = (const float*)d_in[2];
    const float* decay  = (const float*)d_in[3];
    float* out = (float*)d_out;

    // Workspace layout
    const size_t wb_bytes = (size_t)OUT_ * IN_ * 2;                 // 512 KB bf16 W
    const size_t le_bytes = (size_t)(M_ / BM) * OUT_ * 4;           // 512 KB localend
    const size_t fl_bytes = 4096;                                   // flags+ticket
    const size_t need = wb_bytes + le_bytes + fl_bytes;

    if (ws_size >= need) {
        char* w = (char*)d_ws;
        unsigned short* Wb  = (unsigned short*)w;
        float* localend     = (float*)(w + wb_bytes);
        unsigned int* flags = (unsigned int*)(w + wb_bytes + le_bytes);

        convert_w_init<<<(OUT_ * IN_ / 4) / 256, 256, 0, stream>>>(weight, Wb, flags);
        fused_all<<<M_ / BM, THREADS, 0, stream>>>(inputs, Wb, bias, decay,
                                                   out, localend, flags);
    } else {
        dim3 g(OUT_ / 64, M_ / 64);
        gemm_bias<<<g, 256, 0, stream>>>(inputs, weight, bias, out);
        scan_simple<<<B_, OUT_, 0, stream>>>(out, decay);
    }
}